// Round 17
// baseline (921.575 us; speedup 1.0000x reference)
//
#include <hip/hip_runtime.h>
#include <hip/hip_bf16.h>
#include <stdint.h>

typedef __attribute__((ext_vector_type(4))) float f32x4;
typedef __attribute__((ext_vector_type(8))) short short8v;

typedef __attribute__((address_space(1))) void gvoid;
typedef __attribute__((address_space(3))) void lvoid;

#define GLD16(gp, lp) __builtin_amdgcn_global_load_lds((const gvoid*)(gp), (lvoid*)(lp), 16, 0, 0)

__device__ __forceinline__ unsigned short f2bf(float f) {
    union { float ff; unsigned uu; } a; a.ff = f;
    unsigned u = a.uu;
    u += 0x7FFFu + ((u >> 16) & 1u);   // RNE; inputs finite
    return (unsigned short)(u >> 16);
}

// ---- fused: Ub[o][r] = bf16(U[o][r]*(S[r]+eps[r]))  (blocks 0..8191)
//             VtT[k][r] = bf16(Vt[r][k])              (blocks 8192..12287)
__global__ __launch_bounds__(256) void prep_fused_kernel(
    const float* __restrict__ U, const float* __restrict__ S,
    const float* __restrict__ eps, unsigned short* __restrict__ Ub,
    const float* __restrict__ Vt, unsigned short* __restrict__ VtT) {
    __shared__ float tile[64][65];
    if (blockIdx.x < 8192) {
        long idx = ((long)blockIdx.x * 256 + threadIdx.x) * 8;
        int r = (int)(idx & 4095);
        f32x4 u0 = *(const f32x4*)(U + idx);
        f32x4 u1 = *(const f32x4*)(U + idx + 4);
        f32x4 s0 = *(const f32x4*)(S + r);
        f32x4 s1 = *(const f32x4*)(S + r + 4);
        f32x4 e0 = *(const f32x4*)(eps + r);
        f32x4 e1 = *(const f32x4*)(eps + r + 4);
        union { uint4 v; unsigned short s[8]; } o;
#pragma unroll
        for (int j = 0; j < 4; ++j) {
            o.s[j]     = f2bf(u0[j] * (s0[j] + e0[j]));
            o.s[j + 4] = f2bf(u1[j] * (s1[j] + e1[j]));
        }
        *(uint4*)(Ub + idx) = o.v;
    } else {
        int t  = blockIdx.x - 8192;
        int k0 = (t & 63) << 6;
        int r0 = (t >> 6) << 6;
        int tx = threadIdx.x & 63;
        int tq = threadIdx.x >> 6;
#pragma unroll
        for (int i = 0; i < 16; ++i) {
            int row = (i << 2) + tq;
            tile[row][tx] = Vt[(long)(r0 + row) * 4096 + k0 + tx];
        }
        __syncthreads();
#pragma unroll
        for (int i = 0; i < 16; ++i) {
            int krow = (i << 2) + tq;
            VtT[(long)(k0 + krow) * 4096 + r0 + tx] = f2bf(tile[tx][krow]);
        }
    }
}

// ---- generic fp32 -> bf16 convert (fallback path only) ----
__global__ __launch_bounds__(256) void cvt_bf16_kernel(
    const float* __restrict__ src, unsigned short* __restrict__ dst) {
    long idx = ((long)blockIdx.x * 256 + threadIdx.x) * 8;
    f32x4 v0 = *(const f32x4*)(src + idx);
    f32x4 v1 = *(const f32x4*)(src + idx + 4);
    union { uint4 v; unsigned short s[8]; } o;
#pragma unroll
    for (int j = 0; j < 4; ++j) {
        o.s[j]     = f2bf(v0[j]);
        o.s[j + 4] = f2bf(v1[j]);
    }
    *(uint4*)(dst + idx) = o.v;
}

// =====================================================================
// 256x256-tile NT GEMM, REG-DIRECT A + LDS-staged B.  4 phases/iter.
// C[M][N] = A[M][K] * B[N][K]^T (+bias). bf16 in, fp32 acc.
// 512 thr = 8 waves (2M x 4N), wave tile 128x64, BK=32/phase.
//
// (r16 crashed re-validation: cvt loads were INLINE-ASM defs of
// xv0/xv1 — the compiler never inserts a vmcnt wait for asm-defined
// registers, and the f2bf consumer (pure VALU) could be scheduled
// before the VMW walls -> read before the load landed (rule-18
// mechanism on vmcnt). FIX: cvt loads/stores are PLAIN C++ now, so the
// compiler tracks the dataflow and emits precise counted waits. vmem
// counts per phase unchanged (13 / 12 at i==0) — plain ops cannot
// cross the VMW "memory" walls.)
//
// Model (r6-r14): barrier-paced waves alternate [read-burst|MFMA-burst]
// nearly serially; burst length ~ LDS bytes. A fragments load DIRECTLY
// global->reg (double-banked one phase ahead, plain C++); A's 4x wave
// redundancy absorbed by L1 (8KB/wwr-half working set). LDS holds only
// B: 4-region ring of [256 rows][32 k] (16KB each), XOR swizzle
// slot^=(row>>1)&3 both-sides (0 conflicts r3-r14). LDS reads drop
// 96->32 KB/phase: read-burst ~376 cyc << MFMA 1242.
//
// Phase t: { 4x B ds_read r(t%4); A loads bank (t+1)&1 @k=32(t+1) [8];
//   stage B r((t+2)%4) @k=32(t+2) [2]; vmcnt(10); MFMA32 bank t&1;
//   s_barrier }.
// Ring audit: B RAW: stage@t drained by vmcnt(10)@t+1 + barrier, read
// @t+2. B WAR: read@t completes before t's MFMA (compiler lgkm) ->
// before t's barrier; re-stage @t+2. A RAW: bank loaded@t drained by
// vmcnt(10)@t+1 (compiler also inserts its own counted wait). Prologue
// {Bst r0, Bst r1, A-b0} = 12 ops + vmcnt(10) drains r0; rest drained
// @t0's wait. Tail wraps dead (in-bounds k=0 reload).
// =====================================================================
#define MM(a, b, c) __builtin_amdgcn_mfma_f32_16x16x32_bf16(a, b, c, 0, 0, 0)

#define BRG(r) (Bs + (r) * 8192)

#define STAGE_B(r, koff) do { \
    const unsigned short* _s = B + gBr + (koff); \
    unsigned short* _d = BRG(r) + wave * 512; \
    GLD16(_s, _d); GLD16(_s + (long)128 * K, _d + 4096); } while (0)

// 8 A-frag loads, global -> bank bk (literal), at element-k offset kk.
#define LOAD_A_G(bk, kk) do { \
    const unsigned short* _b = A + aGbase + (kk); \
    _Pragma("unroll") \
    for (int _h = 0; _h < 2; ++_h) \
    _Pragma("unroll") \
    for (int _m = 0; _m < 4; ++_m) \
        aR[bk][_h][_m] = *(const short8v*)(_b + (long)(_h * 64 + _m * 16) * K); \
} while (0)

#define READ_B4(rd) do { \
    const unsigned short* _p = BRG(rd) + bBase; \
    _Pragma("unroll") \
    for (int _n = 0; _n < 4; ++_n) bR[_n] = *(const short8v*)(_p + _n * 512); \
} while (0)

#define MFMA32(bk) do { \
    __builtin_amdgcn_s_setprio(1); \
    _Pragma("unroll") \
    for (int _h = 0; _h < 2; ++_h) \
    _Pragma("unroll") \
    for (int _m = 0; _m < 4; ++_m) { \
        acc[_h*4+_m][0] = MM(aR[bk][_h][_m], bR[0], acc[_h*4+_m][0]); \
        acc[_h*4+_m][1] = MM(aR[bk][_h][_m], bR[1], acc[_h*4+_m][1]); \
        acc[_h*4+_m][2] = MM(aR[bk][_h][_m], bR[2], acc[_h*4+_m][2]); \
        acc[_h*4+_m][3] = MM(aR[bk][_h][_m], bR[3], acc[_h*4+_m][3]); \
    } \
    __builtin_amdgcn_s_setprio(0); } while (0)

#define VMW(n) asm volatile("s_waitcnt vmcnt(" #n ")" ::: "memory")
#define BAR __builtin_amdgcn_s_barrier()

// Phase: rd = B region to read, st = B region to stage @ element sk,
// lk = A k-offset for next bank lb, cb = bank to compute.
#define PHASE(rd, st, sk, lk, lb, cb) do { \
    READ_B4(rd); \
    LOAD_A_G(lb, lk); \
    STAGE_B(st, sk); \
    VMW(10); \
    MFMA32(cb); \
    BAR; } while (0)

template<int OUT_BF16, int BIAS, int DO_CVT>
__global__ __launch_bounds__(512, 2) void gemm256_kernel(
    const unsigned short* __restrict__ A,   // [M][K] bf16 bits
    const unsigned short* __restrict__ B,   // [N][K] bf16 bits
    void* __restrict__ Cv, const float* __restrict__ bias,
    const float* __restrict__ xsrc, unsigned short* __restrict__ xdst,
    int M, int N, int K) {
    __shared__ unsigned short Bs[4 * 8192];   // 64 KB (B ring only)

    const int tid  = threadIdx.x;
    const int wave = tid >> 6;
    const int lane = tid & 63;
    const int fr   = lane & 15;
    const int fq   = lane >> 4;

    // XCD-aware bijective swizzle + n-pair clustering (r12, verified)
    const int nwg = gridDim.x;
    const int bid = blockIdx.x;
    const int cpx = nwg >> 3;
    const int wg  = (bid & 7) * cpx + (bid >> 3);
    const int nmt = M >> 8;
    const long n0 = (long)(2 * (wg / cpx) + (wg & 1)) << 8;
    const long m0 = (long)((wg >> 1) & (nmt - 1)) << 8;

    const int wwr = wave >> 2;   // 0..1  (M half)
    const int wwc = wave & 3;    // 0..3  (N quarter)

    // B stage addressing (verified r3-r14): region [256 rows][32 k],
    // 1024 16B slots; global src slot = (si&3) ^ ((row>>1)&3).
    const int  rS  = tid >> 2;                        // rows rS and rS+128
    const int  sS  = (tid & 3) ^ ((rS >> 1) & 3);
    const long gBr = (n0 + rS) * K + sS * 8;

    // B ds_read (swizzled): elem = row*32 + ((fq ^ ((row>>1)&3))*8)
    const int swz   = (fq ^ ((fr >> 1) & 3)) * 8;
    const int bBase = (wwc * 64 + fr) * 32 + swz;

    // A reg-direct base: row = m0 + wwr*128 (+h*64+m*16) + fr, col fq*8
    const long aGbase = (m0 + wwr * 128 + fr) * K + fq * 8;

    f32x4  acc[8][4] = {};
    short8v aR[2][2][4], bR[4];

    // cvt weave state (GEMM1 only): 8 f32 per thread per iter, all
    // PLAIN C++ (compiler-tracked waits — r16 asm defs were the race).
    f32x4 xv0, xv1;
    const float* xp = nullptr;
    unsigned short* xs = nullptr;
    if constexpr (DO_CVT) {
        long base = (long)bid * 4096 + (long)tid * 8;
        xp = xsrc + base;
        xs = xdst + base;
    }

    // Prologue: stage B r0@k0 (2), r1@k32 (2), A bank0 @k0 (8).
    STAGE_B(0, 0);
    STAGE_B(1, 32);
    LOAD_A_G(0, 0);
    VMW(10);
    BAR;

    const int nIter = K >> 7;   // 4 phases x K=32 per iteration
    for (int i = 0; i < nIter; ++i) {
        const int k2 = 128 * i + 64;                    // in-bounds
        const int k3 = 128 * i + 96;                    // in-bounds
        int k4 = 128 * i + 128; if (k4 >= K) k4 -= K;   // wrap: dead
        int k5 = 128 * i + 160; if (k5 >= K) k5 -= K;

        if constexpr (DO_CVT) {
            // t0 + cvt weave: store chunk i-1, load chunk i (plain).
            READ_B4(0);
            if (i) {
                union { uint4 v; unsigned short s[8]; } o;
#pragma unroll
                for (int j = 0; j < 4; ++j) {
                    o.s[j]     = f2bf(xv0[j]);
                    o.s[j + 4] = f2bf(xv1[j]);
                }
                *(uint4*)xs = o.v;
                xs += 1048576;          // 1,048,576 bf16 chip-wide / iter
            }
            xv0 = *(const f32x4*)(xp);
            xv1 = *(const f32x4*)(xp + 4);
            xp += 1048576;              // 1,048,576 f32 chip-wide / iter
            LOAD_A_G(1, 128 * i + 32);
            STAGE_B(2, k2);
            if (i) VMW(13); else VMW(12);
            MFMA32(0);
            BAR;
        } else {
            PHASE(0, 2, k2, 128 * i + 32, 1, 0);   // t0
        }
        PHASE(1, 3, k3, 128 * i + 64, 0, 1);       // t1
        PHASE(2, 0, k4, 128 * i + 96, 1, 0);       // t2
        PHASE(3, 1, k5, k4,            0, 1);      // t3 (A wrap: dead)
    }

    if constexpr (DO_CVT) {      // final chunk store (compiler waits)
        union { uint4 v; unsigned short s[8]; } o;
#pragma unroll
        for (int j = 0; j < 4; ++j) {
            o.s[j]     = f2bf(xv0[j]);
            o.s[j + 4] = f2bf(xv1[j]);
        }
        *(uint4*)xs = o.v;
    }

    // Epilogue: C/D layout col = lane&15, row = (lane>>4)*4 + j
#pragma unroll
    for (int nf = 0; nf < 4; ++nf) {
        const int col = (int)n0 + wwc * 64 + nf * 16 + fr;
        float bv = BIAS ? bias[col] : 0.0f;
#pragma unroll
        for (int mf = 0; mf < 8; ++mf) {
            f32x4 v = acc[mf][nf];
            long rowb = m0 + wwr * 128 + mf * 16 + fq * 4;
#pragma unroll
            for (int j = 0; j < 4; ++j) {
                float val = v[j] + bv;
                long off = (rowb + j) * N + col;
                if (OUT_BF16) ((unsigned short*)Cv)[off] = f2bf(val);
                else          ((float*)Cv)[off] = val;
            }
        }
    }
}

extern "C" void kernel_launch(void* const* d_in, const int* in_sizes, int n_in,
                              void* d_out, int out_size, void* d_ws, size_t ws_size,
                              hipStream_t stream) {
    const float* x    = (const float*)d_in[0];   // [4,2048,4096] = [8192][4096]
    const float* U    = (const float*)d_in[1];   // [4096][4096]
    const float* S    = (const float*)d_in[2];   // [4096]
    const float* Vt   = (const float*)d_in[3];   // [4096][4096]
    const float* eps  = (const float*)d_in[4];   // [4096]
    const float* bias = (const float*)d_in[5];   // [4096]
    float* out = (float*)d_out;                  // [8192][4096] fp32

    char* ws = (char*)d_ws;
    unsigned short* Ub  = (unsigned short*)(ws);                       // 32 MB
    unsigned short* VtT = (unsigned short*)(ws + (size_t)(32 << 20));  // 32 MB
    unsigned short* Wb  = (unsigned short*)(ws + (size_t)(64 << 20));  // 32 MB

    // 1) Ub = bf16(U*(S+eps)) ; VtT = bf16(Vt^T)   (fused, independent)
    prep_fused_kernel<<<12288, 256, 0, stream>>>(U, S, eps, Ub, Vt, VtT);

    if (ws_size >= ((size_t)160 << 20)) {
        // Fused path: GEMM1 also streams x -> Xb (at ws+96MB, no alias).
        unsigned short* Xb = (unsigned short*)(ws + ((size_t)96 << 20));
        gemm256_kernel<1, 0, 1><<<256, 512, 0, stream>>>(
            Ub, VtT, (void*)Wb, nullptr, x, Xb, 4096, 4096, 4096);
        gemm256_kernel<0, 1, 0><<<512, 512, 0, stream>>>(
            Xb, Wb, (void*)out, bias, nullptr, nullptr, 8192, 4096, 4096);
    } else {
        // Fallback: sequential cvt, Xb over Ub/VtT (dead after GEMM1).
        unsigned short* Xb = (unsigned short*)(ws);
        gemm256_kernel<1, 0, 0><<<256, 512, 0, stream>>>(
            Ub, VtT, (void*)Wb, nullptr, nullptr, nullptr, 4096, 4096, 4096);
        cvt_bf16_kernel<<<16384, 256, 0, stream>>>(x, Xb);
        gemm256_kernel<0, 1, 0><<<512, 512, 0, stream>>>(
            Xb, Wb, (void*)out, bias, nullptr, nullptr, 8192, 4096, 4096);
    }
}

// Round 19
// 428.508 us; speedup vs baseline: 2.1507x; 2.1507x over previous
//
#include <hip/hip_runtime.h>
#include <hip/hip_bf16.h>
#include <stdint.h>

typedef __attribute__((ext_vector_type(4))) float f32x4;
typedef __attribute__((ext_vector_type(8))) short short8v;

typedef __attribute__((address_space(1))) void gvoid;
typedef __attribute__((address_space(3))) void lvoid;

#define GLD16(gp, lp) __builtin_amdgcn_global_load_lds((const gvoid*)(gp), (lvoid*)(lp), 16, 0, 0)

__device__ __forceinline__ unsigned short f2bf(float f) {
    union { float ff; unsigned uu; } a; a.ff = f;
    unsigned u = a.uu;
    u += 0x7FFFu + ((u >> 16) & 1u);   // RNE; inputs finite
    return (unsigned short)(u >> 16);
}

// ---- fused: Ub[o][r] = bf16(U[o][r]*(S[r]+eps[r]))  (blocks 0..8191)
//             VtT[k][r] = bf16(Vt[r][k])              (blocks 8192..12287)
__global__ __launch_bounds__(256) void prep_fused_kernel(
    const float* __restrict__ U, const float* __restrict__ S,
    const float* __restrict__ eps, unsigned short* __restrict__ Ub,
    const float* __restrict__ Vt, unsigned short* __restrict__ VtT) {
    __shared__ float tile[64][65];
    if (blockIdx.x < 8192) {
        long idx = ((long)blockIdx.x * 256 + threadIdx.x) * 8;
        int r = (int)(idx & 4095);
        f32x4 u0 = *(const f32x4*)(U + idx);
        f32x4 u1 = *(const f32x4*)(U + idx + 4);
        f32x4 s0 = *(const f32x4*)(S + r);
        f32x4 s1 = *(const f32x4*)(S + r + 4);
        f32x4 e0 = *(const f32x4*)(eps + r);
        f32x4 e1 = *(const f32x4*)(eps + r + 4);
        union { uint4 v; unsigned short s[8]; } o;
#pragma unroll
        for (int j = 0; j < 4; ++j) {
            o.s[j]     = f2bf(u0[j] * (s0[j] + e0[j]));
            o.s[j + 4] = f2bf(u1[j] * (s1[j] + e1[j]));
        }
        *(uint4*)(Ub + idx) = o.v;
    } else {
        int t  = blockIdx.x - 8192;
        int k0 = (t & 63) << 6;
        int r0 = (t >> 6) << 6;
        int tx = threadIdx.x & 63;
        int tq = threadIdx.x >> 6;
#pragma unroll
        for (int i = 0; i < 16; ++i) {
            int row = (i << 2) + tq;
            tile[row][tx] = Vt[(long)(r0 + row) * 4096 + k0 + tx];
        }
        __syncthreads();
#pragma unroll
        for (int i = 0; i < 16; ++i) {
            int krow = (i << 2) + tq;
            VtT[(long)(k0 + krow) * 4096 + r0 + tx] = f2bf(tile[tx][krow]);
        }
    }
}

// ---- generic fp32 -> bf16 convert (fallback path only) ----
__global__ __launch_bounds__(256) void cvt_bf16_kernel(
    const float* __restrict__ src, unsigned short* __restrict__ dst) {
    long idx = ((long)blockIdx.x * 256 + threadIdx.x) * 8;
    f32x4 v0 = *(const f32x4*)(src + idx);
    f32x4 v1 = *(const f32x4*)(src + idx + 4);
    union { uint4 v; unsigned short s[8]; } o;
#pragma unroll
    for (int j = 0; j < 4; ++j) {
        o.s[j]     = f2bf(v0[j]);
        o.s[j + 4] = f2bf(v1[j]);
    }
    *(uint4*)(dst + idx) = o.v;
}

// =====================================================================
// 256x256-tile NT GEMM, 4 phases/iter, counted-lgkm pipeline + T19 SGB
// (r11/r12 structure) + DO_CVT weave — GEMM1 additionally streams
// the x f32->bf16 conversion (1 chunk of 8 f32 per thread per iter, in
// P1), hiding the former 35us cvt kernel under GEMM1's idle HBM.
// === RESTORED r13 VERBATIM (best measured: 426.3us total, GEMM2
// 241.5us / 1139 TF / 54% MfmaUtil / 0 bank conflicts). Safety proof
// of the asm cvt loads: consumed 4 phases after issue; hardware-drained
// by the intervening VMW(4) (7 cvt+t0-stage ops + 4 t1-stages -> drain
// to 4 leaves only t1 stages); consumer cannot hoist past the four
// intervening sched_barrier(0) walls. r18's plain-C++ variant let cvt
// ops float across s_barrier builtins (not compiler fences) and broke
// the hand-counted ring -> fault. ===
//
// vmcnt ring with cvt (gfx9: stores count in vmcnt, ISA doc §5/§7):
//  P1 window = st1 + ld2 + stage4 = 7  -> vmcnt(7)  (i==0: 6 -> vmcnt(6))
//  P2..P4 unchanged vmcnt(4).
//  - prev P4's stages confirmed by P1-end vmcnt(7) (drains oldest 4) OK
//  - P1's stages confirmed by P2-end vmcnt(4) (drains P1's 7) before
//    P3's reads OK; cvt loads drained there too, consumed next P1 OK
//  - convert-hoist blocked by per-phase sched_barrier(0) walls (rule 18)
// Xb lives at ws+96MB (no alias with live Ub/VtT); gated on
// ws_size >= 160MB, else the sequential path runs unchanged.
// =====================================================================
#define MM(a, b, c) __builtin_amdgcn_mfma_f32_16x16x32_bf16(a, b, c, 0, 0, 0)

#define ARG(r) (As + (r) * 8192)
#define BRG(r) (Bs + (r) * 8192)

#define STAGE_A(r, koff) do { \
    const unsigned short* _s = A + gAr + (koff); \
    unsigned short* _d = ARG(r) + wave * 512; \
    GLD16(_s, _d); GLD16(_s + (long)128 * K, _d + 4096); } while (0)

#define STAGE_B(r, koff) do { \
    const unsigned short* _s = B + gBr + (koff); \
    unsigned short* _d = BRG(r) + wave * 512; \
    GLD16(_s, _d); GLD16(_s + (long)128 * K, _d + 4096); } while (0)

// inline-asm ds_read_b128, volatile, no "memory" clobber (r11)
#define DSR(dst, base, imm) \
    asm volatile("ds_read_b128 %0, %1 offset:%c2" \
                 : "=v"(dst) : "v"(base), "i"(imm))

#define READ_AB(bk, R) do { \
    DSR(aB[bk][0][0], aByte, (R)*16384 + 0);            \
    DSR(aB[bk][0][1], aByte, (R)*16384 + 1024);         \
    DSR(aB[bk][0][2], aByte, (R)*16384 + 2048);         \
    DSR(aB[bk][0][3], aByte, (R)*16384 + 3072);         \
    DSR(aB[bk][1][0], aByte, (R)*16384 + 4096);         \
    DSR(aB[bk][1][1], aByte, (R)*16384 + 5120);         \
    DSR(aB[bk][1][2], aByte, (R)*16384 + 6144);         \
    DSR(aB[bk][1][3], aByte, (R)*16384 + 7168);         \
    DSR(bB[bk][0],    bByte, (R)*16384 + 0);            \
    DSR(bB[bk][1],    bByte, (R)*16384 + 1024);         \
    DSR(bB[bk][2],    bByte, (R)*16384 + 2048);         \
    DSR(bB[bk][3],    bByte, (R)*16384 + 3072); } while (0)

#define MFMA32(bk) do { \
    _Pragma("unroll") \
    for (int _h = 0; _h < 2; ++_h) \
    _Pragma("unroll") \
    for (int _m = 0; _m < 4; ++_m) { \
        acc[_h*4+_m][0] = MM(aB[bk][_h][_m], bB[bk][0], acc[_h*4+_m][0]); \
        acc[_h*4+_m][1] = MM(aB[bk][_h][_m], bB[bk][1], acc[_h*4+_m][1]); \
        acc[_h*4+_m][2] = MM(aB[bk][_h][_m], bB[bk][2], acc[_h*4+_m][2]); \
        acc[_h*4+_m][3] = MM(aB[bk][_h][_m], bB[bk][3], acc[_h*4+_m][3]); \
    } } while (0)

#define SGB __builtin_amdgcn_sched_group_barrier

#define SGB_PATTERN do { \
    _Pragma("unroll") \
    for (int _g = 0; _g < 12; ++_g) { SGB(0x008, 2, 0); SGB(0x100, 1, 0); } \
    SGB(0x008, 8, 0); } while (0)

#define PHASE(rN, sb, rS, sk, cb) do { \
    STAGE_A(rS, sk); STAGE_B(rS, sk); \
    asm volatile("s_waitcnt lgkmcnt(0)" ::: "memory"); \
    __builtin_amdgcn_sched_barrier(0); \
    __builtin_amdgcn_s_setprio(1); \
    READ_AB(sb, rN); \
    MFMA32(cb); \
    SGB_PATTERN; \
    __builtin_amdgcn_s_setprio(0); \
    asm volatile("s_waitcnt vmcnt(4)" ::: "memory"); \
    __builtin_amdgcn_s_barrier(); } while (0)

#define XCVT_STORE do { \
    union { uint4 v; unsigned short s[8]; } _o; \
    _Pragma("unroll") \
    for (int _j = 0; _j < 4; ++_j) { \
        _o.s[_j]     = f2bf(xv0[_j]); \
        _o.s[_j + 4] = f2bf(xv1[_j]); } \
    *reinterpret_cast<uint4*>((uintptr_t)xsaddr) = _o.v; \
    xsaddr += 2097152ull; } while (0)

template<int OUT_BF16, int BIAS, int DO_CVT>
__global__ __launch_bounds__(512, 2) void gemm256_kernel(
    const unsigned short* __restrict__ A,   // [M][K] bf16 bits
    const unsigned short* __restrict__ B,   // [N][K] bf16 bits
    void* __restrict__ Cv, const float* __restrict__ bias,
    const float* __restrict__ xsrc, unsigned short* __restrict__ xdst,
    int M, int N, int K) {
    __shared__ unsigned short As[4 * 8192];   // 64 KB
    __shared__ unsigned short Bs[4 * 8192];   // 64 KB

    const int tid  = threadIdx.x;
    const int wave = tid >> 6;
    const int lane = tid & 63;
    const int fr   = lane & 15;
    const int fq   = lane >> 4;

    // XCD-aware bijective swizzle + n-pair clustering (r12)
    const int nwg = gridDim.x;
    const int bid = blockIdx.x;
    const int cpx = nwg >> 3;
    const int wg  = (bid & 7) * cpx + (bid >> 3);
    const int nmt = M >> 8;
    const long n0 = (long)(2 * (wg / cpx) + (wg & 1)) << 8;
    const long m0 = (long)((wg >> 1) & (nmt - 1)) << 8;

    const int wwr = wave >> 2;   // 0..1  (M half)
    const int wwc = wave & 3;    // 0..3  (N quarter)

    // Stage addressing (verified): region chunk [256 rows][32 k] bf16,
    // 1024 16B slots; global src slot = (si&3) ^ ((row>>1)&3).
    const int  rS  = tid >> 2;                        // rows rS and rS+128
    const int  sS  = (tid & 3) ^ ((rS >> 1) & 3);
    const long gAr = (m0 + rS) * K + sS * 8;
    const long gBr = (n0 + rS) * K + sS * 8;

    // ds_read (swizzled): elem = row*32 + ((fq ^ ((row>>1)&3))*8)
    const int swz   = (fq ^ ((fr >> 1) & 3)) * 8;
    const int aBase = (wwr * 128 + fr) * 32 + swz;
    const int bBase = (wwc * 64 + fr) * 32 + swz;
    const unsigned aByte = (unsigned)(uintptr_t)(As + aBase);
    const unsigned bByte = (unsigned)(uintptr_t)(Bs + bBase);

    f32x4  acc[8][4] = {};
    short8v aB[2][2][4], bB[2][4];

    // cvt weave state (GEMM1 only): 8 f32 per thread per iter.
    f32x4 xv0, xv1;
    unsigned long long xaddr = 0, xsaddr = 0;
    if constexpr (DO_CVT) {
        long gchunk = ((long)bid * 512 + tid);
        xaddr  = (unsigned long long)(uintptr_t)(xsrc + gchunk * 8);
        xsaddr = (unsigned long long)(uintptr_t)(xdst + gchunk * 8);
    }

    // Prologue: stage r0@k0, r1@k32, r2@k64; vmcnt(4) confirms r0,r1
    // (r2 confirmed by t=0's phase-end wait); read r0 -> bank0.
    STAGE_A(0, 0);  STAGE_B(0, 0);
    STAGE_A(1, 32); STAGE_B(1, 32);
    STAGE_A(2, 64); STAGE_B(2, 64);
    asm volatile("s_waitcnt vmcnt(4)" ::: "memory");
    __builtin_amdgcn_s_barrier();
    READ_AB(0, 0);

    const int nIter = K >> 7;   // 4 phases x K=32 per iteration
    for (int i = 0; i < nIter; ++i) {
        const int kA = 128 * i + 96;                    // in-bounds
        int k0n = 128 * i + 128; if (k0n >= K) k0n -= K; // wrap: dead
        int k1n = 128 * i + 160; if (k1n >= K) k1n -= K;
        int k2n = 128 * i + 192; if (k2n >= K) k2n -= K;

        if constexpr (DO_CVT) {
            // P1 with cvt weave: store chunk i-1, load chunk i.
            if (i) XCVT_STORE;
            asm volatile("global_load_dwordx4 %0, %2, off\n\t"
                         "global_load_dwordx4 %1, %2, off offset:16"
                         : "=&v"(xv0), "=&v"(xv1) : "v"(xaddr));
            xaddr += 4194304ull;
            STAGE_A(3, kA); STAGE_B(3, kA);
            asm volatile("s_waitcnt lgkmcnt(0)" ::: "memory");
            __builtin_amdgcn_sched_barrier(0);
            __builtin_amdgcn_s_setprio(1);
            READ_AB(1, 1);
            MFMA32(0);
            SGB_PATTERN;
            __builtin_amdgcn_s_setprio(0);
            if (i) asm volatile("s_waitcnt vmcnt(7)" ::: "memory");
            else   asm volatile("s_waitcnt vmcnt(6)" ::: "memory");
            __builtin_amdgcn_s_barrier();
        } else {
            PHASE(1, 1, 3, kA,  0);   // t0: read r1->b1, stage r3, mfma b0
        }
        PHASE(2, 0, 0, k0n, 1);       // t1: read r2->b0, stage r0, mfma b1
        PHASE(3, 1, 1, k1n, 0);       // t2: read r3->b1, stage r1, mfma b0
        PHASE(0, 0, 2, k2n, 1);       // t3: read r0->b0, stage r2, mfma b1
    }

    if constexpr (DO_CVT) XCVT_STORE;   // chunk nIter-1 (loads long drained)

    // Epilogue: C/D layout col = lane&15, row = (lane>>4)*4 + j
#pragma unroll
    for (int nf = 0; nf < 4; ++nf) {
        const int col = (int)n0 + wwc * 64 + nf * 16 + fr;
        float bv = BIAS ? bias[col] : 0.0f;
#pragma unroll
        for (int mf = 0; mf < 8; ++mf) {
            f32x4 v = acc[mf][nf];
            long rowb = m0 + wwr * 128 + mf * 16 + fq * 4;
#pragma unroll
            for (int j = 0; j < 4; ++j) {
                float val = v[j] + bv;
                long off = (rowb + j) * N + col;
                if (OUT_BF16) ((unsigned short*)Cv)[off] = f2bf(val);
                else          ((float*)Cv)[off] = val;
            }
        }
    }
}

extern "C" void kernel_launch(void* const* d_in, const int* in_sizes, int n_in,
                              void* d_out, int out_size, void* d_ws, size_t ws_size,
                              hipStream_t stream) {
    const float* x    = (const float*)d_in[0];   // [4,2048,4096] = [8192][4096]
    const float* U    = (const float*)d_in[1];   // [4096][4096]
    const float* S    = (const float*)d_in[2];   // [4096]
    const float* Vt   = (const float*)d_in[3];   // [4096][4096]
    const float* eps  = (const float*)d_in[4];   // [4096]
    const float* bias = (const float*)d_in[5];   // [4096]
    float* out = (float*)d_out;                  // [8192][4096] fp32

    char* ws = (char*)d_ws;
    unsigned short* Ub  = (unsigned short*)(ws);                       // 32 MB
    unsigned short* VtT = (unsigned short*)(ws + (size_t)(32 << 20));  // 32 MB
    unsigned short* Wb  = (unsigned short*)(ws + (size_t)(64 << 20));  // 32 MB

    // 1) Ub = bf16(U*(S+eps)) ; VtT = bf16(Vt^T)   (fused, independent)
    prep_fused_kernel<<<12288, 256, 0, stream>>>(U, S, eps, Ub, Vt, VtT);

    if (ws_size >= ((size_t)160 << 20)) {
        // Fused path: GEMM1 also streams x -> Xb (at ws+96MB, no alias).
        unsigned short* Xb = (unsigned short*)(ws + ((size_t)96 << 20));
        gemm256_kernel<1, 0, 1><<<256, 512, 0, stream>>>(
            Ub, VtT, (void*)Wb, nullptr, x, Xb, 4096, 4096, 4096);
        gemm256_kernel<0, 1, 0><<<512, 512, 0, stream>>>(
            Xb, Wb, (void*)out, bias, nullptr, nullptr, 8192, 4096, 4096);
    } else {
        // Fallback: sequential cvt, Xb over Ub/VtT (dead after GEMM1).
        unsigned short* Xb = (unsigned short*)(ws);
        gemm256_kernel<1, 0, 0><<<256, 512, 0, stream>>>(
            Ub, VtT, (void*)Wb, nullptr, nullptr, nullptr, 4096, 4096, 4096);
        cvt_bf16_kernel<<<16384, 256, 0, stream>>>(x, Xb);
        gemm256_kernel<0, 1, 0><<<512, 512, 0, stream>>>(
            Xb, Wb, (void*)out, bias, nullptr, nullptr, 8192, 4096, 4096);
    }
}

// Round 21
// 428.312 us; speedup vs baseline: 2.1516x; 1.0005x over previous
//
#include <hip/hip_runtime.h>
#include <hip/hip_bf16.h>
#include <stdint.h>

typedef __attribute__((ext_vector_type(4))) float f32x4;
typedef __attribute__((ext_vector_type(8))) short short8v;

typedef __attribute__((address_space(1))) void gvoid;
typedef __attribute__((address_space(3))) void lvoid;

#define GLD16(gp, lp) __builtin_amdgcn_global_load_lds((const gvoid*)(gp), (lvoid*)(lp), 16, 0, 0)

__device__ __forceinline__ unsigned short f2bf(float f) {
    union { float ff; unsigned uu; } a; a.ff = f;
    unsigned u = a.uu;
    u += 0x7FFFu + ((u >> 16) & 1u);   // RNE; inputs finite
    return (unsigned short)(u >> 16);
}

// ---- fused: Ub[o][r] = bf16(U[o][r]*(S[r]+eps[r]))  (blocks 0..8191)
//             VtT[k][r] = bf16(Vt[r][k])              (blocks 8192..12287)
__global__ __launch_bounds__(256) void prep_fused_kernel(
    const float* __restrict__ U, const float* __restrict__ S,
    const float* __restrict__ eps, unsigned short* __restrict__ Ub,
    const float* __restrict__ Vt, unsigned short* __restrict__ VtT) {
    __shared__ float tile[64][65];
    if (blockIdx.x < 8192) {
        long idx = ((long)blockIdx.x * 256 + threadIdx.x) * 8;
        int r = (int)(idx & 4095);
        f32x4 u0 = *(const f32x4*)(U + idx);
        f32x4 u1 = *(const f32x4*)(U + idx + 4);
        f32x4 s0 = *(const f32x4*)(S + r);
        f32x4 s1 = *(const f32x4*)(S + r + 4);
        f32x4 e0 = *(const f32x4*)(eps + r);
        f32x4 e1 = *(const f32x4*)(eps + r + 4);
        union { uint4 v; unsigned short s[8]; } o;
#pragma unroll
        for (int j = 0; j < 4; ++j) {
            o.s[j]     = f2bf(u0[j] * (s0[j] + e0[j]));
            o.s[j + 4] = f2bf(u1[j] * (s1[j] + e1[j]));
        }
        *(uint4*)(Ub + idx) = o.v;
    } else {
        int t  = blockIdx.x - 8192;
        int k0 = (t & 63) << 6;
        int r0 = (t >> 6) << 6;
        int tx = threadIdx.x & 63;
        int tq = threadIdx.x >> 6;
#pragma unroll
        for (int i = 0; i < 16; ++i) {
            int row = (i << 2) + tq;
            tile[row][tx] = Vt[(long)(r0 + row) * 4096 + k0 + tx];
        }
        __syncthreads();
#pragma unroll
        for (int i = 0; i < 16; ++i) {
            int krow = (i << 2) + tq;
            VtT[(long)(k0 + krow) * 4096 + r0 + tx] = f2bf(tile[tx][krow]);
        }
    }
}

// ---- generic fp32 -> bf16 convert (fallback path only) ----
__global__ __launch_bounds__(256) void cvt_bf16_kernel(
    const float* __restrict__ src, unsigned short* __restrict__ dst) {
    long idx = ((long)blockIdx.x * 256 + threadIdx.x) * 8;
    f32x4 v0 = *(const f32x4*)(src + idx);
    f32x4 v1 = *(const f32x4*)(src + idx + 4);
    union { uint4 v; unsigned short s[8]; } o;
#pragma unroll
    for (int j = 0; j < 4; ++j) {
        o.s[j]     = f2bf(v0[j]);
        o.s[j + 4] = f2bf(v1[j]);
    }
    *(uint4*)(dst + idx) = o.v;
}

// =====================================================================
// 256x256-tile NT GEMM, 4 phases/iter, counted-lgkm pipeline + T19 SGB
// (r11/r12 structure) + DO_CVT weave — GEMM1 additionally streams
// the x f32->bf16 conversion (1 chunk of 8 f32 per thread per iter, in
// P1), hiding the former 35us cvt kernel under GEMM1's idle HBM.
// === r13/r19 BASIN KERNEL, FINAL (verified twice: 426.3us / 428.5us
// total; GEMM2 241.5us / 1139 TF / 54% MfmaUtil / 0 bank conflicts).
// r20's wave-role-split faulted: s_barrier is convergent and cannot
// live under a wave-divergent branch (compiler may if-convert /
// restructure -> barrier/exec corruption). Uniform schedule restored.
// Safety of the asm cvt loads: consumed 4 phases after issue; drained
// by the intervening VMW(4) (7 cvt+t0-stage ops + 4 t1-stages -> drain
// to 4 leaves only t1 stages); consumer cannot hoist past the four
// intervening sched_barrier(0) walls. ===
//
// vmcnt ring with cvt (gfx9: stores count in vmcnt, ISA doc §5/§7):
//  P1 window = st1 + ld2 + stage4 = 7  -> vmcnt(7)  (i==0: 6 -> vmcnt(6))
//  P2..P4 unchanged vmcnt(4).
//  - prev P4's stages confirmed by P1-end vmcnt(7) (drains oldest 4) OK
//  - P1's stages confirmed by P2-end vmcnt(4) (drains P1's 7) before
//    P3's reads OK; cvt loads drained there too, consumed next P1 OK
//  - convert-hoist blocked by per-phase sched_barrier(0) walls (rule 18)
// Xb lives at ws+96MB (no alias with live Ub/VtT); gated on
// ws_size >= 160MB, else the sequential path runs unchanged.
// =====================================================================
#define MM(a, b, c) __builtin_amdgcn_mfma_f32_16x16x32_bf16(a, b, c, 0, 0, 0)

#define ARG(r) (As + (r) * 8192)
#define BRG(r) (Bs + (r) * 8192)

#define STAGE_A(r, koff) do { \
    const unsigned short* _s = A + gAr + (koff); \
    unsigned short* _d = ARG(r) + wave * 512; \
    GLD16(_s, _d); GLD16(_s + (long)128 * K, _d + 4096); } while (0)

#define STAGE_B(r, koff) do { \
    const unsigned short* _s = B + gBr + (koff); \
    unsigned short* _d = BRG(r) + wave * 512; \
    GLD16(_s, _d); GLD16(_s + (long)128 * K, _d + 4096); } while (0)

// inline-asm ds_read_b128, volatile, no "memory" clobber (r11)
#define DSR(dst, base, imm) \
    asm volatile("ds_read_b128 %0, %1 offset:%c2" \
                 : "=v"(dst) : "v"(base), "i"(imm))

#define READ_AB(bk, R) do { \
    DSR(aB[bk][0][0], aByte, (R)*16384 + 0);            \
    DSR(aB[bk][0][1], aByte, (R)*16384 + 1024);         \
    DSR(aB[bk][0][2], aByte, (R)*16384 + 2048);         \
    DSR(aB[bk][0][3], aByte, (R)*16384 + 3072);         \
    DSR(aB[bk][1][0], aByte, (R)*16384 + 4096);         \
    DSR(aB[bk][1][1], aByte, (R)*16384 + 5120);         \
    DSR(aB[bk][1][2], aByte, (R)*16384 + 6144);         \
    DSR(aB[bk][1][3], aByte, (R)*16384 + 7168);         \
    DSR(bB[bk][0],    bByte, (R)*16384 + 0);            \
    DSR(bB[bk][1],    bByte, (R)*16384 + 1024);         \
    DSR(bB[bk][2],    bByte, (R)*16384 + 2048);         \
    DSR(bB[bk][3],    bByte, (R)*16384 + 3072); } while (0)

#define MFMA32(bk) do { \
    _Pragma("unroll") \
    for (int _h = 0; _h < 2; ++_h) \
    _Pragma("unroll") \
    for (int _m = 0; _m < 4; ++_m) { \
        acc[_h*4+_m][0] = MM(aB[bk][_h][_m], bB[bk][0], acc[_h*4+_m][0]); \
        acc[_h*4+_m][1] = MM(aB[bk][_h][_m], bB[bk][1], acc[_h*4+_m][1]); \
        acc[_h*4+_m][2] = MM(aB[bk][_h][_m], bB[bk][2], acc[_h*4+_m][2]); \
        acc[_h*4+_m][3] = MM(aB[bk][_h][_m], bB[bk][3], acc[_h*4+_m][3]); \
    } } while (0)

#define SGB __builtin_amdgcn_sched_group_barrier

#define SGB_PATTERN do { \
    _Pragma("unroll") \
    for (int _g = 0; _g < 12; ++_g) { SGB(0x008, 2, 0); SGB(0x100, 1, 0); } \
    SGB(0x008, 8, 0); } while (0)

#define PHASE(rN, sb, rS, sk, cb) do { \
    STAGE_A(rS, sk); STAGE_B(rS, sk); \
    asm volatile("s_waitcnt lgkmcnt(0)" ::: "memory"); \
    __builtin_amdgcn_sched_barrier(0); \
    __builtin_amdgcn_s_setprio(1); \
    READ_AB(sb, rN); \
    MFMA32(cb); \
    SGB_PATTERN; \
    __builtin_amdgcn_s_setprio(0); \
    asm volatile("s_waitcnt vmcnt(4)" ::: "memory"); \
    __builtin_amdgcn_s_barrier(); } while (0)

#define XCVT_STORE do { \
    union { uint4 v; unsigned short s[8]; } _o; \
    _Pragma("unroll") \
    for (int _j = 0; _j < 4; ++_j) { \
        _o.s[_j]     = f2bf(xv0[_j]); \
        _o.s[_j + 4] = f2bf(xv1[_j]); } \
    *reinterpret_cast<uint4*>((uintptr_t)xsaddr) = _o.v; \
    xsaddr += 2097152ull; } while (0)

template<int OUT_BF16, int BIAS, int DO_CVT>
__global__ __launch_bounds__(512, 2) void gemm256_kernel(
    const unsigned short* __restrict__ A,   // [M][K] bf16 bits
    const unsigned short* __restrict__ B,   // [N][K] bf16 bits
    void* __restrict__ Cv, const float* __restrict__ bias,
    const float* __restrict__ xsrc, unsigned short* __restrict__ xdst,
    int M, int N, int K) {
    __shared__ unsigned short As[4 * 8192];   // 64 KB
    __shared__ unsigned short Bs[4 * 8192];   // 64 KB

    const int tid  = threadIdx.x;
    const int wave = tid >> 6;
    const int lane = tid & 63;
    const int fr   = lane & 15;
    const int fq   = lane >> 4;

    // XCD-aware bijective swizzle + n-pair clustering (r12)
    const int nwg = gridDim.x;
    const int bid = blockIdx.x;
    const int cpx = nwg >> 3;
    const int wg  = (bid & 7) * cpx + (bid >> 3);
    const int nmt = M >> 8;
    const long n0 = (long)(2 * (wg / cpx) + (wg & 1)) << 8;
    const long m0 = (long)((wg >> 1) & (nmt - 1)) << 8;

    const int wwr = wave >> 2;   // 0..1  (M half)
    const int wwc = wave & 3;    // 0..3  (N quarter)

    // Stage addressing (verified): region chunk [256 rows][32 k] bf16,
    // 1024 16B slots; global src slot = (si&3) ^ ((row>>1)&3).
    const int  rS  = tid >> 2;                        // rows rS and rS+128
    const int  sS  = (tid & 3) ^ ((rS >> 1) & 3);
    const long gAr = (m0 + rS) * K + sS * 8;
    const long gBr = (n0 + rS) * K + sS * 8;

    // ds_read (swizzled): elem = row*32 + ((fq ^ ((row>>1)&3))*8)
    const int swz   = (fq ^ ((fr >> 1) & 3)) * 8;
    const int aBase = (wwr * 128 + fr) * 32 + swz;
    const int bBase = (wwc * 64 + fr) * 32 + swz;
    const unsigned aByte = (unsigned)(uintptr_t)(As + aBase);
    const unsigned bByte = (unsigned)(uintptr_t)(Bs + bBase);

    f32x4  acc[8][4] = {};
    short8v aB[2][2][4], bB[2][4];

    // cvt weave state (GEMM1 only): 8 f32 per thread per iter.
    f32x4 xv0, xv1;
    unsigned long long xaddr = 0, xsaddr = 0;
    if constexpr (DO_CVT) {
        long gchunk = ((long)bid * 512 + tid);
        xaddr  = (unsigned long long)(uintptr_t)(xsrc + gchunk * 8);
        xsaddr = (unsigned long long)(uintptr_t)(xdst + gchunk * 8);
    }

    // Prologue: stage r0@k0, r1@k32, r2@k64; vmcnt(4) confirms r0,r1
    // (r2 confirmed by t=0's phase-end wait); read r0 -> bank0.
    STAGE_A(0, 0);  STAGE_B(0, 0);
    STAGE_A(1, 32); STAGE_B(1, 32);
    STAGE_A(2, 64); STAGE_B(2, 64);
    asm volatile("s_waitcnt vmcnt(4)" ::: "memory");
    __builtin_amdgcn_s_barrier();
    READ_AB(0, 0);

    const int nIter = K >> 7;   // 4 phases x K=32 per iteration
    for (int i = 0; i < nIter; ++i) {
        const int kA = 128 * i + 96;                    // in-bounds
        int k0n = 128 * i + 128; if (k0n >= K) k0n -= K; // wrap: dead
        int k1n = 128 * i + 160; if (k1n >= K) k1n -= K;
        int k2n = 128 * i + 192; if (k2n >= K) k2n -= K;

        if constexpr (DO_CVT) {
            // P1 with cvt weave: store chunk i-1, load chunk i.
            if (i) XCVT_STORE;
            asm volatile("global_load_dwordx4 %0, %2, off\n\t"
                         "global_load_dwordx4 %1, %2, off offset:16"
                         : "=&v"(xv0), "=&v"(xv1) : "v"(xaddr));
            xaddr += 4194304ull;
            STAGE_A(3, kA); STAGE_B(3, kA);
            asm volatile("s_waitcnt lgkmcnt(0)" ::: "memory");
            __builtin_amdgcn_sched_barrier(0);
            __builtin_amdgcn_s_setprio(1);
            READ_AB(1, 1);
            MFMA32(0);
            SGB_PATTERN;
            __builtin_amdgcn_s_setprio(0);
            if (i) asm volatile("s_waitcnt vmcnt(7)" ::: "memory");
            else   asm volatile("s_waitcnt vmcnt(6)" ::: "memory");
            __builtin_amdgcn_s_barrier();
        } else {
            PHASE(1, 1, 3, kA,  0);   // t0: read r1->b1, stage r3, mfma b0
        }
        PHASE(2, 0, 0, k0n, 1);       // t1: read r2->b0, stage r0, mfma b1
        PHASE(3, 1, 1, k1n, 0);       // t2: read r3->b1, stage r1, mfma b0
        PHASE(0, 0, 2, k2n, 1);       // t3: read r0->b0, stage r2, mfma b1
    }

    if constexpr (DO_CVT) XCVT_STORE;   // chunk nIter-1 (loads long drained)

    // Epilogue: C/D layout col = lane&15, row = (lane>>4)*4 + j
#pragma unroll
    for (int nf = 0; nf < 4; ++nf) {
        const int col = (int)n0 + wwc * 64 + nf * 16 + fr;
        float bv = BIAS ? bias[col] : 0.0f;
#pragma unroll
        for (int mf = 0; mf < 8; ++mf) {
            f32x4 v = acc[mf][nf];
            long rowb = m0 + wwr * 128 + mf * 16 + fq * 4;
#pragma unroll
            for (int j = 0; j < 4; ++j) {
                float val = v[j] + bv;
                long off = (rowb + j) * N + col;
                if (OUT_BF16) ((unsigned short*)Cv)[off] = f2bf(val);
                else          ((float*)Cv)[off] = val;
            }
        }
    }
}

extern "C" void kernel_launch(void* const* d_in, const int* in_sizes, int n_in,
                              void* d_out, int out_size, void* d_ws, size_t ws_size,
                              hipStream_t stream) {
    const float* x    = (const float*)d_in[0];   // [4,2048,4096] = [8192][4096]
    const float* U    = (const float*)d_in[1];   // [4096][4096]
    const float* S    = (const float*)d_in[2];   // [4096]
    const float* Vt   = (const float*)d_in[3];   // [4096][4096]
    const float* eps  = (const float*)d_in[4];   // [4096]
    const float* bias = (const float*)d_in[5];   // [4096]
    float* out = (float*)d_out;                  // [8192][4096] fp32

    char* ws = (char*)d_ws;
    unsigned short* Ub  = (unsigned short*)(ws);                       // 32 MB
    unsigned short* VtT = (unsigned short*)(ws + (size_t)(32 << 20));  // 32 MB
    unsigned short* Wb  = (unsigned short*)(ws + (size_t)(64 << 20));  // 32 MB

    // 1) Ub = bf16(U*(S+eps)) ; VtT = bf16(Vt^T)   (fused, independent)
    prep_fused_kernel<<<12288, 256, 0, stream>>>(U, S, eps, Ub, Vt, VtT);

    if (ws_size >= ((size_t)160 << 20)) {
        // Fused path: GEMM1 also streams x -> Xb (at ws+96MB, no alias).
        unsigned short* Xb = (unsigned short*)(ws + ((size_t)96 << 20));
        gemm256_kernel<1, 0, 1><<<256, 512, 0, stream>>>(
            Ub, VtT, (void*)Wb, nullptr, x, Xb, 4096, 4096, 4096);
        gemm256_kernel<0, 1, 0><<<512, 512, 0, stream>>>(
            Xb, Wb, (void*)out, bias, nullptr, nullptr, 8192, 4096, 4096);
    } else {
        // Fallback: sequential cvt, Xb over Ub/VtT (dead after GEMM1).
        unsigned short* Xb = (unsigned short*)(ws);
        gemm256_kernel<1, 0, 0><<<256, 512, 0, stream>>>(
            Ub, VtT, (void*)Wb, nullptr, nullptr, nullptr, 4096, 4096, 4096);
        cvt_bf16_kernel<<<16384, 256, 0, stream>>>(x, Xb);
        gemm256_kernel<0, 1, 0><<<512, 512, 0, stream>>>(
            Xb, Wb, (void*)out, bias, nullptr, nullptr, 8192, 4096, 4096);
    }
}